// Round 3
// baseline (146.850 us; speedup 1.0000x reference)
//
#include <hip/hip_runtime.h>
#include <cstdint>
#include <cstddef>

typedef short bfrag __attribute__((ext_vector_type(8)));   // 8 bf16 (4 VGPR)
typedef float facc  __attribute__((ext_vector_type(4)));   // 4 f32 acc

namespace {
constexpr int B = 128, N = 2048, A = 16, M = 64, D = 16;
constexpr int NA = N * A;            // 32768 (GEMM K)
constexpr int MD = M * D;            // 1024  (GEMM N)
constexpr size_t C_ELEMS = (size_t)B * MD;  // 131072
}

static __device__ __forceinline__ ushort f2bf(float x) {  // RNE f32->bf16
    uint u = __float_as_uint(x);
    u += 0x7fffu + ((u >> 16) & 1u);
    return (ushort)(u >> 16);
}
static __device__ __forceinline__ bfrag ld_frag16(const ushort* p) {  // 16B-aligned
    union { uint4 q; bfrag v; } u;
    u.q = *(const uint4*)p;
    return u.v;
}
static __device__ __forceinline__ bfrag ld_frag4(const ushort* p) {   // 4B-aligned
    const uint* q = (const uint*)p;
    union { uint a[4]; bfrag v; } u;
    u.a[0] = q[0]; u.a[1] = q[1]; u.a[2] = q[2]; u.a[3] = q[3];
    return u.v;
}

// ---------------------------------------------------------------------------
// k1: split-K bf16 MFMA GEMM. part[chunk][b][md] = sum_{na in chunk} in*w
// (unchanged from R2 — measured ~84% of its 235 MB HBM floor)
// ---------------------------------------------------------------------------
__global__ __launch_bounds__(512, 2) void k1_mfma(const float* __restrict__ in,
                                                  const float* __restrict__ w,
                                                  float* __restrict__ part,
                                                  int nch) {
    const int mdg   = blockIdx.x;              // md0 = 256*mdg
    const int chunk = blockIdx.y;
    const int t     = threadIdx.x;
    const int nap   = NA / nch;                // na per chunk
    const int nkt   = nap / 64;
    __shared__ __align__(16) ushort in_t[128 * 72];  // [b][k] rows 144B (16B-aligned)
    __shared__ __align__(16) ushort w_t[256 * 66];   // [md][k] rows 132B (4B-aligned reads)
    const int wv = t >> 6, tl = t & 63;
    const int wb = wv >> 2, wm = wv & 3;       // wave: b-half, md-quarter
    const int lr = tl & 15, hi = tl >> 4;

    facc acc[4][4];
    #pragma unroll
    for (int i = 0; i < 4; ++i)
        #pragma unroll
        for (int j = 0; j < 4; ++j) acc[i][j] = facc{0.f, 0.f, 0.f, 0.f};

    float4 pin[4], pw[8];
    const int ib  = t >> 4, ik = t & 15;       // in-stage: +q*32 b rows
    const int wk  = t >> 6, wmd = t & 63;      // w-stage: +q*8 k rows

    int na0 = (size_t)chunk * nap;
    // prologue loads (KT 0)
    #pragma unroll
    for (int q = 0; q < 4; ++q)
        pin[q] = *(const float4*)(in + (size_t)(q * 32 + ib) * NA + na0 + ik * 4);
    #pragma unroll
    for (int q = 0; q < 8; ++q)
        pw[q] = *(const float4*)(w + (size_t)(na0 + q * 8 + wk) * MD + mdg * 256 + wmd * 4);

    for (int kt = 0; kt < nkt; ++kt) {
        __syncthreads();                       // prev compute done reading LDS
        // stage regs -> LDS (bf16), w transposed
        #pragma unroll
        for (int q = 0; q < 4; ++q) {
            union { ushort s[4]; uint2 u; } pk;
            pk.s[0] = f2bf(pin[q].x); pk.s[1] = f2bf(pin[q].y);
            pk.s[2] = f2bf(pin[q].z); pk.s[3] = f2bf(pin[q].w);
            *(uint2*)(&in_t[(q * 32 + ib) * 72 + ik * 4]) = pk.u;
        }
        #pragma unroll
        for (int q = 0; q < 8; ++q) {
            const int krow = q * 8 + wk;
            w_t[(wmd * 4 + 0) * 66 + krow] = f2bf(pw[q].x);
            w_t[(wmd * 4 + 1) * 66 + krow] = f2bf(pw[q].y);
            w_t[(wmd * 4 + 2) * 66 + krow] = f2bf(pw[q].z);
            w_t[(wmd * 4 + 3) * 66 + krow] = f2bf(pw[q].w);
        }
        __syncthreads();
        if (kt + 1 < nkt) {                    // prefetch next KT (overlaps MFMA)
            const int nan = na0 + 64;
            #pragma unroll
            for (int q = 0; q < 4; ++q)
                pin[q] = *(const float4*)(in + (size_t)(q * 32 + ib) * NA + nan + ik * 4);
            #pragma unroll
            for (int q = 0; q < 8; ++q)
                pw[q] = *(const float4*)(w + (size_t)(nan + q * 8 + wk) * MD + mdg * 256 + wmd * 4);
        }
        // compute KT: 2 k-steps (K=32) x 16 MFMA
        #pragma unroll
        for (int ks = 0; ks < 2; ++ks) {
            bfrag af[4], bf[4];
            #pragma unroll
            for (int bt = 0; bt < 4; ++bt)
                af[bt] = ld_frag16(&in_t[(wb * 64 + bt * 16 + lr) * 72 + ks * 32 + hi * 8]);
            #pragma unroll
            for (int mt = 0; mt < 4; ++mt)
                bf[mt] = ld_frag4(&w_t[(wm * 64 + mt * 16 + lr) * 66 + ks * 32 + hi * 8]);
            #pragma unroll
            for (int bt = 0; bt < 4; ++bt)
                #pragma unroll
                for (int mt = 0; mt < 4; ++mt)
                    acc[bt][mt] = __builtin_amdgcn_mfma_f32_16x16x32_bf16(
                        af[bt], bf[mt], acc[bt][mt], 0, 0, 0);
        }
        na0 += 64;
    }
    // store partials: C row = 4*hi + r (b), col = lane&15 (md)
    #pragma unroll
    for (int bt = 0; bt < 4; ++bt)
        #pragma unroll
        for (int mt = 0; mt < 4; ++mt) {
            const int b  = wb * 64 + bt * 16 + hi * 4;
            const int md = mdg * 256 + wm * 64 + mt * 16 + lr;
            #pragma unroll
            for (int r = 0; r < 4; ++r)
                part[((size_t)chunk * B + b + r) * MD + md] = acc[bt][mt][r];
        }
}

// ---------------------------------------------------------------------------
// k2: reduce partials -> v_raw -> squash -> v_sq (ws); LayerNorm -> out_v
// ---------------------------------------------------------------------------
__global__ __launch_bounds__(256) void k2_squash_ln(const float* __restrict__ part,
                                                    const float* __restrict__ gamma,
                                                    const float* __restrict__ beta,
                                                    float* __restrict__ v_sq,
                                                    float* __restrict__ out_v,
                                                    int nch) {
    const int idx = blockIdx.x * 256 + threadIdx.x;   // (b*64+m)*16+d
    const int d   = idx & 15;
    float s = 0.f;
    for (int c = 0; c < nch; ++c) s += part[(size_t)c * C_ELEMS + idx];
    const float v = s * (1.0f / 64.0f);               // uniform routing 1/m
    float sq = v * v;
    #pragma unroll
    for (int off = 1; off < 16; off <<= 1) sq += __shfl_xor(sq, off, 16);
    const float f  = sqrtf(sq) / (1.0f + sq);         // squash factor
    const float vs = v * f;
    v_sq[idx] = vs;
    float mu = vs;
    #pragma unroll
    for (int off = 1; off < 16; off <<= 1) mu += __shfl_xor(mu, off, 16);
    mu *= (1.0f / 16.0f);
    const float dd = vs - mu;
    float var = dd * dd;
    #pragma unroll
    for (int off = 1; off < 16; off <<= 1) var += __shfl_xor(var, off, 16);
    var *= (1.0f / 16.0f);
    out_v[idx] = dd / sqrtf(var + 1e-5f) * gamma[d] + beta[d];
}

// ---------------------------------------------------------------------------
// k3 v2: qk[b,n,m] = sum_d (sum_a in[b,n,a] w[n,a,m,d]) * v_sq[b,m,d]
// grid (4 m-groups of 16, 128 n-segs of 16), 512 thr = 8 waves = 8 b-groups.
// Per n: A=w^T (rows=d, K=a pad32), B=in^T (cols=b); C row=4hi+r=d, col=lr=b.
// w_t LDS layout [mi][ag][d][8] => A-frag ds_read_b128 at lane*16 (m134
// throughput pattern); XOR swizzle ^(mi&7)<<3 fixes 32-way staging-write
// conflict, reads unaffected (mi wave-uniform). Double-buffered, 1 barrier/n,
// reg-prefetch of n+1. Epilogue: 4 FMA vs reg-resident vsq + shfl_xor(16,32).
// ---------------------------------------------------------------------------
__global__ __launch_bounds__(512, 2) void k3_mfma(const float* __restrict__ in,
                                                  const float* __restrict__ w,
                                                  const float* __restrict__ vsq,
                                                  float* __restrict__ qk) {
    const int m0 = blockIdx.x * 16;
    const int n0 = blockIdx.y * 16;
    const int t  = threadIdx.x;
    const int wv = t >> 6, tl = t & 63;
    const int lr = tl & 15, hi = tl >> 4;
    const int b  = wv * 16 + lr;                      // this lane's output b
    __shared__ __align__(16) ushort w_t[2][4096];     // [mi][ag][d][8] ^ swz
    __shared__ __align__(16) ushort in_t[2][2048];    // [b][a]

    float4 vsr[16];                                   // vsq[b][m0+mi][4hi..+3]
    #pragma unroll
    for (int mi = 0; mi < 16; ++mi)
        vsr[mi] = *(const float4*)(vsq + ((size_t)b * M + m0 + mi) * D + hi * 4);

    float4 pw[2], pin;
    auto ldg = [&](int n) {
        #pragma unroll
        for (int q = 0; q < 2; ++q) {
            const int idx = q * 512 + t;
            const int a = idx >> 6, mloc = (idx >> 2) & 15, d4 = idx & 3;
            pw[q] = *(const float4*)(
                w + (((size_t)n * A + a) * M + m0 + mloc) * D + d4 * 4);
        }
        pin = *(const float4*)(in + (size_t)(t >> 2) * NA + n * A + (t & 3) * 4);
    };
    auto stg = [&](int p) {
        #pragma unroll
        for (int q = 0; q < 2; ++q) {
            const int idx = q * 512 + t;
            const int a = idx >> 6, mloc = (idx >> 2) & 15, d4 = idx & 3;
            const int base = mloc * 256 + (a >> 3) * 128 + (a & 7);
            const int swz  = (mloc & 7) << 3;
            w_t[p][(base + (d4 * 4 + 0) * 8) ^ swz] = f2bf(pw[q].x);
            w_t[p][(base + (d4 * 4 + 1) * 8) ^ swz] = f2bf(pw[q].y);
            w_t[p][(base + (d4 * 4 + 2) * 8) ^ swz] = f2bf(pw[q].z);
            w_t[p][(base + (d4 * 4 + 3) * 8) ^ swz] = f2bf(pw[q].w);
        }
        union { ushort s[4]; uint2 u; } pk;
        pk.s[0] = f2bf(pin.x); pk.s[1] = f2bf(pin.y);
        pk.s[2] = f2bf(pin.z); pk.s[3] = f2bf(pin.w);
        *(uint2*)(&in_t[p][(t >> 2) * 16 + (t & 3) * 4]) = pk.u;
    };

    ldg(n0);
    stg(0);
    __syncthreads();
    for (int i = 0; i < 16; ++i) {
        const int p = i & 1;
        if (i + 1 < 16) ldg(n0 + i + 1);              // global->reg, hides HBM
        // B-frag: in^T[a, b]; upper-K lanes zeroed (K=16 padded to 32)
        uint4 braw = *(const uint4*)&in_t[p][b * 16 + (hi & 1) * 8];
        if (hi >= 2) { braw.x = 0u; braw.y = 0u; braw.z = 0u; braw.w = 0u; }
        union { uint4 q; bfrag v; } bu; bu.q = braw;
        const facc zero = facc{0.f, 0.f, 0.f, 0.f};
        float out4[4];
        #pragma unroll
        for (int mi = 0; mi < 16; ++mi) {
            const int ridx = (mi * 256 + (hi & 1) * 128 + lr * 8) ^ ((mi & 7) << 3);
            uint4 araw = *(const uint4*)&w_t[p][ridx];
            if (hi >= 2) { araw.x = 0u; araw.y = 0u; araw.z = 0u; araw.w = 0u; }
            union { uint4 q; bfrag v; } au; au.q = araw;
            const facc c = __builtin_amdgcn_mfma_f32_16x16x32_bf16(au.v, bu.v, zero, 0, 0, 0);
            float s = c[0] * vsr[mi].x + c[1] * vsr[mi].y
                    + c[2] * vsr[mi].z + c[3] * vsr[mi].w;
            s += __shfl_xor(s, 16);
            s += __shfl_xor(s, 32);                   // full d-sum across hi
            if ((mi >> 2) == hi) out4[mi & 3] = s;    // owner quad keeps it
        }
        const float4 o = {out4[0], out4[1], out4[2], out4[3]};
        *(float4*)(qk + ((size_t)b * N + n0 + i) * M + m0 + hi * 4) = o;
        if (i + 1 < 16) {
            stg(p ^ 1);                               // write OTHER buffer
            __syncthreads();                          // one barrier per n
        }
    }
}

// ---------------------------------------------------------------------------
extern "C" void kernel_launch(void* const* d_in, const int* in_sizes, int n_in,
                              void* d_out, int out_size, void* d_ws, size_t ws_size,
                              hipStream_t stream) {
    const float* in    = (const float*)d_in[0];
    const float* w     = (const float*)d_in[1];
    const float* gamma = (const float*)d_in[2];
    const float* beta  = (const float*)d_in[3];
    float* out_qk = (float*)d_out;
    float* out_v  = out_qk + (size_t)B * N * M;

    int nch = 64;
    if (ws_size < (64 + 1) * C_ELEMS * sizeof(float)) nch = 16;
    if (ws_size < (16 + 1) * C_ELEMS * sizeof(float)) nch = 8;
    float* part = (float*)d_ws;
    float* vsq  = part + (size_t)nch * C_ELEMS;

    k1_mfma<<<dim3(4, nch), 512, 0, stream>>>(in, w, part, nch);
    k2_squash_ln<<<(int)(C_ELEMS / 256), 256, 0, stream>>>(part, gamma, beta, vsq, out_v, nch);
    k3_mfma<<<dim3(4, 128), 512, 0, stream>>>(in, w, vsq, out_qk);
}

// Round 4
// 138.260 us; speedup vs baseline: 1.0621x; 1.0621x over previous
//
#include <hip/hip_runtime.h>
#include <cstdint>
#include <cstddef>

typedef short bfrag __attribute__((ext_vector_type(8)));   // 8 bf16 (4 VGPR)
typedef float facc  __attribute__((ext_vector_type(4)));   // 4 f32 acc

namespace {
constexpr int B = 128, N = 2048, A = 16, M = 64, D = 16;
constexpr int NA = N * A;            // 32768 (GEMM K)
constexpr int MD = M * D;            // 1024  (GEMM N)
constexpr size_t C_ELEMS = (size_t)B * MD;  // 131072
}

static __device__ __forceinline__ ushort f2bf(float x) {  // RNE f32->bf16
    uint u = __float_as_uint(x);
    u += 0x7fffu + ((u >> 16) & 1u);
    return (ushort)(u >> 16);
}
static __device__ __forceinline__ bfrag ld_frag16(const ushort* p) {  // 16B-aligned
    union { uint4 q; bfrag v; } u;
    u.q = *(const uint4*)p;
    return u.v;
}
static __device__ __forceinline__ bfrag ld_frag4(const ushort* p) {   // 4B-aligned
    const uint* q = (const uint*)p;
    union { uint a[4]; bfrag v; } u;
    u.a[0] = q[0]; u.a[1] = q[1]; u.a[2] = q[2]; u.a[3] = q[3];
    return u.v;
}

// ---------------------------------------------------------------------------
// k1: split-K bf16 MFMA GEMM. part[chunk][b][md] = sum_{na in chunk} in*w
// (unchanged from R2 — measured ~84% of its 235 MB HBM floor)
// ---------------------------------------------------------------------------
__global__ __launch_bounds__(512, 2) void k1_mfma(const float* __restrict__ in,
                                                  const float* __restrict__ w,
                                                  float* __restrict__ part,
                                                  int nch) {
    const int mdg   = blockIdx.x;              // md0 = 256*mdg
    const int chunk = blockIdx.y;
    const int t     = threadIdx.x;
    const int nap   = NA / nch;                // na per chunk
    const int nkt   = nap / 64;
    __shared__ __align__(16) ushort in_t[128 * 72];  // [b][k] rows 144B (16B-aligned)
    __shared__ __align__(16) ushort w_t[256 * 66];   // [md][k] rows 132B (4B-aligned reads)
    const int wv = t >> 6, tl = t & 63;
    const int wb = wv >> 2, wm = wv & 3;       // wave: b-half, md-quarter
    const int lr = tl & 15, hi = tl >> 4;

    facc acc[4][4];
    #pragma unroll
    for (int i = 0; i < 4; ++i)
        #pragma unroll
        for (int j = 0; j < 4; ++j) acc[i][j] = facc{0.f, 0.f, 0.f, 0.f};

    float4 pin[4], pw[8];
    const int ib  = t >> 4, ik = t & 15;       // in-stage: +q*32 b rows
    const int wk  = t >> 6, wmd = t & 63;      // w-stage: +q*8 k rows

    int na0 = (size_t)chunk * nap;
    // prologue loads (KT 0)
    #pragma unroll
    for (int q = 0; q < 4; ++q)
        pin[q] = *(const float4*)(in + (size_t)(q * 32 + ib) * NA + na0 + ik * 4);
    #pragma unroll
    for (int q = 0; q < 8; ++q)
        pw[q] = *(const float4*)(w + (size_t)(na0 + q * 8 + wk) * MD + mdg * 256 + wmd * 4);

    for (int kt = 0; kt < nkt; ++kt) {
        __syncthreads();                       // prev compute done reading LDS
        // stage regs -> LDS (bf16), w transposed
        #pragma unroll
        for (int q = 0; q < 4; ++q) {
            union { ushort s[4]; uint2 u; } pk;
            pk.s[0] = f2bf(pin[q].x); pk.s[1] = f2bf(pin[q].y);
            pk.s[2] = f2bf(pin[q].z); pk.s[3] = f2bf(pin[q].w);
            *(uint2*)(&in_t[(q * 32 + ib) * 72 + ik * 4]) = pk.u;
        }
        #pragma unroll
        for (int q = 0; q < 8; ++q) {
            const int krow = q * 8 + wk;
            w_t[(wmd * 4 + 0) * 66 + krow] = f2bf(pw[q].x);
            w_t[(wmd * 4 + 1) * 66 + krow] = f2bf(pw[q].y);
            w_t[(wmd * 4 + 2) * 66 + krow] = f2bf(pw[q].z);
            w_t[(wmd * 4 + 3) * 66 + krow] = f2bf(pw[q].w);
        }
        __syncthreads();
        if (kt + 1 < nkt) {                    // prefetch next KT (overlaps MFMA)
            const int nan = na0 + 64;
            #pragma unroll
            for (int q = 0; q < 4; ++q)
                pin[q] = *(const float4*)(in + (size_t)(q * 32 + ib) * NA + nan + ik * 4);
            #pragma unroll
            for (int q = 0; q < 8; ++q)
                pw[q] = *(const float4*)(w + (size_t)(nan + q * 8 + wk) * MD + mdg * 256 + wmd * 4);
        }
        // compute KT: 2 k-steps (K=32) x 16 MFMA
        #pragma unroll
        for (int ks = 0; ks < 2; ++ks) {
            bfrag af[4], bf[4];
            #pragma unroll
            for (int bt = 0; bt < 4; ++bt)
                af[bt] = ld_frag16(&in_t[(wb * 64 + bt * 16 + lr) * 72 + ks * 32 + hi * 8]);
            #pragma unroll
            for (int mt = 0; mt < 4; ++mt)
                bf[mt] = ld_frag4(&w_t[(wm * 64 + mt * 16 + lr) * 66 + ks * 32 + hi * 8]);
            #pragma unroll
            for (int bt = 0; bt < 4; ++bt)
                #pragma unroll
                for (int mt = 0; mt < 4; ++mt)
                    acc[bt][mt] = __builtin_amdgcn_mfma_f32_16x16x32_bf16(
                        af[bt], bf[mt], acc[bt][mt], 0, 0, 0);
        }
        na0 += 64;
    }
    // store partials: C row = 4*hi + r (b), col = lane&15 (md)
    #pragma unroll
    for (int bt = 0; bt < 4; ++bt)
        #pragma unroll
        for (int mt = 0; mt < 4; ++mt) {
            const int b  = wb * 64 + bt * 16 + hi * 4;
            const int md = mdg * 256 + wm * 64 + mt * 16 + lr;
            #pragma unroll
            for (int r = 0; r < 4; ++r)
                part[((size_t)chunk * B + b + r) * MD + md] = acc[bt][mt][r];
        }
}

// ---------------------------------------------------------------------------
// k2: reduce partials -> v_raw -> squash -> v_sq (ws); LayerNorm -> out_v
// ---------------------------------------------------------------------------
__global__ __launch_bounds__(256) void k2_squash_ln(const float* __restrict__ part,
                                                    const float* __restrict__ gamma,
                                                    const float* __restrict__ beta,
                                                    float* __restrict__ v_sq,
                                                    float* __restrict__ out_v,
                                                    int nch) {
    const int idx = blockIdx.x * 256 + threadIdx.x;   // (b*64+m)*16+d
    const int d   = idx & 15;
    float s = 0.f;
    for (int c = 0; c < nch; ++c) s += part[(size_t)c * C_ELEMS + idx];
    const float v = s * (1.0f / 64.0f);               // uniform routing 1/m
    float sq = v * v;
    #pragma unroll
    for (int off = 1; off < 16; off <<= 1) sq += __shfl_xor(sq, off, 16);
    const float f  = sqrtf(sq) / (1.0f + sq);         // squash factor
    const float vs = v * f;
    v_sq[idx] = vs;
    float mu = vs;
    #pragma unroll
    for (int off = 1; off < 16; off <<= 1) mu += __shfl_xor(mu, off, 16);
    mu *= (1.0f / 16.0f);
    const float dd = vs - mu;
    float var = dd * dd;
    #pragma unroll
    for (int off = 1; off < 16; off <<= 1) var += __shfl_xor(var, off, 16);
    var *= (1.0f / 16.0f);
    out_v[idx] = dd / sqrtf(var + 1e-5f) * gamma[d] + beta[d];
}

// ---------------------------------------------------------------------------
// k3 v3: R2 structure (empirically 75us) + 2n per phase + zero-padded rows.
// qk[b,n,m] = sum_d (sum_a in[b,n,a] w[n,a,m,d]) * v_sq[b,m,d]
// grid (4 m-groups of 16, 128 n-segs of 16), 512 thr = 8 waves = 8 b-groups.
// Per n: A=w^T (rows lr=d, K=a, rows 24 with a16..23 ZEROED once so hi>=2
// reads real zeros -> no cndmask), B=in^T (cols lr=b). C row=4hi+r=d ->
// 4 FMA vs reg-resident vsq + shfl_xor(16,32) d-sum; float4 qk stores.
// 8 phases x 2n: barriers halved, prefetch window doubled vs R2.
// ---------------------------------------------------------------------------
__global__ __launch_bounds__(512, 2) void k3_mfma(const float* __restrict__ in,
                                                  const float* __restrict__ w,
                                                  const float* __restrict__ vsq,
                                                  float* __restrict__ qk) {
    const int m0 = blockIdx.x * 16;
    const int n0 = blockIdx.y * 16;
    const int t  = threadIdx.x;
    const int wv = t >> 6, tl = t & 63;
    const int lr = tl & 15, hi = tl >> 4;
    const int b  = wv * 16 + lr;                      // this lane's output b
    // [buf][nn][ (m*16+d)*24 + a ]  rows 48B; a in [16,24) stays zero forever
    __shared__ __align__(16) ushort wt[2][2][6144];   // 49152 B
    __shared__ __align__(16) ushort it[2][2][3072];   // [buf][nn][b*24+a] 24576 B

    // zero-init whole LDS once (pads included); stg only writes a<16 after
    {
        const uint4 z = {0u, 0u, 0u, 0u};
        uint4* z1 = (uint4*)&wt[0][0][0];
        #pragma unroll
        for (int j = 0; j < 6; ++j) z1[j * 512 + t] = z;   // 3072 uint4
        uint4* z2 = (uint4*)&it[0][0][0];
        #pragma unroll
        for (int j = 0; j < 3; ++j) z2[j * 512 + t] = z;   // 1536 uint4
    }

    float4 vsr[16];                                   // vsq[b][m0+mi][4hi..+3]
    #pragma unroll
    for (int mi = 0; mi < 16; ++mi)
        vsr[mi] = *(const float4*)(vsq + ((size_t)b * M + m0 + mi) * D + hi * 4);

    const int sa  = t >> 6, smd = t & 63;             // w-stage coords
    const int mloc = smd >> 2, d0 = (smd & 3) * 4;
    const int sb  = t >> 2, saf = t & 3;              // in-stage coords
    float4 pw[2][2], pin[2];                          // [nn][lo/hi-a], [nn]
    const int koff = (hi < 2) ? hi * 8 : 16;          // hi>=2 -> zero pad (bcast)

    auto ldg = [&](int ph) {
        #pragma unroll
        for (int nn = 0; nn < 2; ++nn) {
            const int n = n0 + ph * 2 + nn;
            pw[nn][0] = *(const float4*)(
                w + (size_t)(n * A + sa) * MD + m0 * D + smd * 4);
            pw[nn][1] = *(const float4*)(
                w + (size_t)(n * A + sa + 8) * MD + m0 * D + smd * 4);
            pin[nn] = *(const float4*)(in + (size_t)sb * NA + n * A + saf * 4);
        }
    };
    auto stg = [&](int p) {
        #pragma unroll
        for (int nn = 0; nn < 2; ++nn) {
            ushort* wb_ = &wt[p][nn][0];
            #pragma unroll
            for (int h = 0; h < 2; ++h) {
                const int a = sa + h * 8;
                wb_[(mloc * 16 + d0 + 0) * 24 + a] = f2bf(pw[nn][h].x);
                wb_[(mloc * 16 + d0 + 1) * 24 + a] = f2bf(pw[nn][h].y);
                wb_[(mloc * 16 + d0 + 2) * 24 + a] = f2bf(pw[nn][h].z);
                wb_[(mloc * 16 + d0 + 3) * 24 + a] = f2bf(pw[nn][h].w);
            }
            union { ushort s[4]; uint2 u; } pk;
            pk.s[0] = f2bf(pin[nn].x); pk.s[1] = f2bf(pin[nn].y);
            pk.s[2] = f2bf(pin[nn].z); pk.s[3] = f2bf(pin[nn].w);
            *(uint2*)(&it[p][nn][sb * 24 + saf * 4]) = pk.u;
        }
    };

    ldg(0);
    __syncthreads();                                  // init-vs-stg ordering
    stg(0);
    ldg(1);
    __syncthreads();                                  // buf0 ready
    for (int ph = 0; ph < 8; ++ph) {
        const int p = ph & 1;
        #pragma unroll
        for (int nn = 0; nn < 2; ++nn) {
            const int n = n0 + ph * 2 + nn;
            const bfrag bf = ld_frag16(&it[p][nn][b * 24 + koff]);
            const facc zero = facc{0.f, 0.f, 0.f, 0.f};
            float out4[4];
            #pragma unroll
            for (int mi = 0; mi < 16; ++mi) {
                const bfrag af = ld_frag16(&wt[p][nn][(mi * 16 + lr) * 24 + koff]);
                const facc c = __builtin_amdgcn_mfma_f32_16x16x32_bf16(af, bf, zero, 0, 0, 0);
                float s = c[0] * vsr[mi].x + c[1] * vsr[mi].y
                        + c[2] * vsr[mi].z + c[3] * vsr[mi].w;
                s += __shfl_xor(s, 16);
                s += __shfl_xor(s, 32);               // full d-sum across hi
                if ((mi >> 2) == hi) out4[mi & 3] = s;
            }
            const float4 o = {out4[0], out4[1], out4[2], out4[3]};
            *(float4*)(qk + ((size_t)b * N + n) * M + m0 + hi * 4) = o;
        }
        __syncthreads();                              // all reads of buf p done
        if (ph < 7) {
            stg(p ^ 1);                               // phase ph+1 (regs landed)
            if (ph < 6) ldg(ph + 2);                  // refill prefetch regs
            __syncthreads();
        }
    }
}

// ---------------------------------------------------------------------------
extern "C" void kernel_launch(void* const* d_in, const int* in_sizes, int n_in,
                              void* d_out, int out_size, void* d_ws, size_t ws_size,
                              hipStream_t stream) {
    const float* in    = (const float*)d_in[0];
    const float* w     = (const float*)d_in[1];
    const float* gamma = (const float*)d_in[2];
    const float* beta  = (const float*)d_in[3];
    float* out_qk = (float*)d_out;
    float* out_v  = out_qk + (size_t)B * N * M;

    int nch = 64;
    if (ws_size < (64 + 1) * C_ELEMS * sizeof(float)) nch = 16;
    if (ws_size < (16 + 1) * C_ELEMS * sizeof(float)) nch = 8;
    float* part = (float*)d_ws;
    float* vsq  = part + (size_t)nch * C_ELEMS;

    k1_mfma<<<dim3(4, nch), 512, 0, stream>>>(in, w, part, nch);
    k2_squash_ln<<<(int)(C_ELEMS / 256), 256, 0, stream>>>(part, gamma, beta, vsq, out_v, nch);
    k3_mfma<<<dim3(4, 128), 512, 0, stream>>>(in, w, vsq, out_qk);
}